// Round 14
// baseline (190.645 us; speedup 1.0000x reference)
//
#include <hip/hip_runtime.h>
#include <math.h>

#define DT   0.1f
#define HDT  0.005f
#define T_HIST 20
#define LEN_PRED 30

typedef __attribute__((ext_vector_type(8))) short bfrag8;   // 8 bf16 = 4 VGPRs
typedef __attribute__((ext_vector_type(4))) float f32x4;
typedef __attribute__((ext_vector_type(2))) unsigned int u32x2;

// d_ws layout (bytes)
#define WS_FRAG   0u        // 96 frags * 512 bf16 * 2B = 98304
#define WS_WIN    98304u    // 2 frags * 1024B (w-major: frag w = Win rows w*16..w*16+15)
#define WS_WOUT   100352u   // 1 frag * 1024B (replicated rows -> pred0..3 in every lane)
#define WS_BIAS   101376u   // 2*3*32*4 floats = 3072B ([ph][l][col][gate])

static __device__ __forceinline__ unsigned short f2bf(float x) {
    union { float f; unsigned int u; } v; v.f = x;
    unsigned int r = v.u + 0x7fffu + ((v.u >> 16) & 1u);   // RNE
    return (unsigned short)(r >> 16);
}

static __device__ __forceinline__ unsigned int cvtpk(float lo, float hi) {
    unsigned int r;
    asm("v_cvt_pk_bf16_f32 %0, %1, %2" : "=v"(r) : "v"(lo), "v"(hi));
    return r;
}

// ---------------- weight prep (UNCHANGED from R7) ----------------
// Layer frag (ph,l,c,t) with t=2*wv+j: A[p][k] = W[gate*32+feat][k],
// gate=p&3, feat = wv*8 + 2*(p>>2) + j.  D row=q*4+r -> lane (q,m) reg r =
// gate r of cell feat wv*8+2q+j; packed c/h dword writes land at
// xch[fg=wv][m][dw=q] (2 lanes/bank, free); reads [q][m] are linear
// lane*16B (conflict-free).
// Win frag (w-major): frag w rows p -> Win row w*16+p.
// Wout frag: REPLICATED rows (p&3) -> every lane's D regs = pred0..3 (no shfl).
// Bias: [ph][l][col=feat][gate].
__global__ void prep_kernel(const float* __restrict__ Win_W,
                            const float* __restrict__ eWih, const float* __restrict__ eWhh,
                            const float* __restrict__ ebih, const float* __restrict__ ebhh,
                            const float* __restrict__ dWih, const float* __restrict__ dWhh,
                            const float* __restrict__ dbih, const float* __restrict__ dbhh,
                            const float* __restrict__ Wout_W,
                            char* __restrict__ ws)
{
    int i = blockIdx.x * blockDim.x + threadIdx.x;
    if (i < 49152) {
        int fi = i >> 9, within = i & 511;
        int lane = within >> 3, jj = within & 7;
        int t = fi & 7, c = (fi >> 3) & 1;
        int pl = fi >> 4;                 // ph*3 + l
        int l = pl % 3, ph = pl / 3;
        int p = lane & 15, q2 = lane >> 4;
        int gate = p & 3;
        int feat = (t >> 1) * 8 + 2 * (p >> 2) + (t & 1);   // (wv,j) mapping
        int row = gate * 32 + feat;
        int k = q2 * 8 + jj;
        const float* W = (c == 0) ? (ph ? dWih : eWih) : (ph ? dWhh : eWhh);
        ((unsigned short*)(ws + WS_FRAG))[i] = f2bf(W[l * 4096 + row * 32 + k]);
    } else if (i < 50176) {
        int i2 = i - 49152;
        int w = i2 >> 9, within = i2 & 511;
        int lane = within >> 3, jj = within & 7;
        int p = lane & 15, q2 = lane >> 4;
        int k = q2 * 8 + jj;
        float v = (k < 24) ? Win_W[(w * 16 + p) * 24 + k] : 0.f;
        ((unsigned short*)(ws + WS_WIN))[i2] = f2bf(v);
    } else if (i < 50688) {
        int i3 = i - 50176;
        int lane = i3 >> 3, jj = i3 & 7;
        int p = lane & 15, q2 = lane >> 4;
        float v = Wout_W[(p & 3) * 32 + q2 * 8 + jj];   // replicated rows
        ((unsigned short*)(ws + WS_WOUT))[i3] = f2bf(v);
    } else if (i < 51456) {
        int b = i - 50688;                 // [ph][l][col][r]
        int ph = b / 384, rem = b % 384;
        int l = rem >> 7, w2 = rem & 127;
        int col = w2 >> 2, r = w2 & 3;
        const float* bi = ph ? dbih : ebih;
        const float* bh = ph ? dbhh : ebhh;
        ((float*)(ws + WS_BIAS))[b] = bi[l * 128 + r * 32 + col] + bh[l * 128 + r * 32 + col];
    }
}

// ---------------- main kernel: 4 waves per 16 batch elems (R7 structure) ----------------
// R14 delta (isolating R12's untested component): KF on waves 2-3 holds BOTH
// channels in registers (R8-proven math). The XP B-fragment is built entirely
// in registers (build_xp: 8 cvtpk) -> regionA loses the stage_xp LDS
// round-trip (18 f2bf + writes + lgkm + ds_read ~120cy) from the decoder's
// serial chain, and the prologue loses the xps buffer entirely.
// Everything else is R7 verbatim: diagonal encoder (21 barriers), 4-barrier
// decoder, hoisted hh-MFMAs, replicated-Wout, native __expf activations.
__launch_bounds__(256, 2)
__global__ void kalman_lstm_kernel(const float* __restrict__ hist,
                                   const float* __restrict__ max_ax, const float* __restrict__ max_ay,
                                   const float* __restrict__ vstd, const float* __restrict__ astd,
                                   const float* __restrict__ Rx_, const float* __restrict__ Ry_,
                                   const float* __restrict__ Gx, const float* __restrict__ Gy,
                                   const float* __restrict__ Win_b, const float* __restrict__ Wout_b,
                                   const char* __restrict__ ws, float* __restrict__ out)
{
    __shared__ __align__(16) unsigned int xchC[3][2][4][16][4]; // [layer][parity][fg][m][dw]
    __shared__ __align__(16) unsigned int xchH[3][2][4][16][4];
    __shared__ __align__(16) unsigned int xenc[T_HIST - 1][4][16][4]; // encoder x0 frags
    __shared__ __align__(16) unsigned int x0b[4][16][4];             // decoder x0 frag

    const int tid  = threadIdx.x;
    const int wv   = tid >> 6;
    const int lane = tid & 63;
    const int q    = lane >> 4;
    const int m    = lane & 15;
    const int be   = blockIdx.x * 16 + m;
    const f32x4 zero4 = {0.f, 0.f, 0.f, 0.f};

    const bfrag8* fragp = (const bfrag8*)(ws + WS_FRAG);
    const f32x4*  biasp = (const f32x4*)(ws + WS_BIAS);

    // ---- per-wave layer weights in registers: [l][c: 0=ih 1=hh][j] ----
    bfrag8 fragA[3][2][2];
    f32x4  biasV[3][2];
    auto load_phase = [&](int ph) {
#pragma unroll
        for (int l = 0; l < 3; ++l) {
#pragma unroll
            for (int c = 0; c < 2; ++c)
#pragma unroll
                for (int j = 0; j < 2; ++j)
                    fragA[l][c][j] = fragp[(((ph * 3 + l) * 2 + c) * 8 + (2 * wv + j)) * 64 + lane];
#pragma unroll
            for (int j = 0; j < 2; ++j)
                biasV[l][j] = biasp[ph * 96 + l * 32 + (wv * 8 + 2 * q + j)];
        }
    };
    load_phase(0);

    // ---- KF-wave operators (waves 2,3; w = wv-2 emits x0 half w) ----
    const int w = (wv >= 2) ? (wv - 2) : 0;
    bfrag8 winF = ((const bfrag8*)(ws + WS_WIN))[w * 64 + lane];
    f32x4 winBv;
#pragma unroll
    for (int r = 0; r < 4; ++r) winBv[r] = Win_b[w * 16 + q * 4 + r];
    bfrag8 woutF = ((const bfrag8*)(ws + WS_WOUT))[lane];
    const float wb0 = Wout_b[0], wb1 = Wout_b[1], wb2 = Wout_b[2], wb3 = Wout_b[3];

    // ---- uniform KF constants (wave-uniform -> SGPRs) ----
    const float rx = Rx_[0] * Rx_[0], ry = Ry_[0] * Ry_[0];
    const float gX0 = Gx[0], gX1 = Gx[1], gX2 = Gx[2];
    const float gY0 = Gy[0], gY1 = Gy[1], gY2 = Gy[2];
    const float gx00 = gX0*gX0, gx01 = gX0*gX1, gx02 = gX0*gX2,
                gx11 = gX1*gX1, gx12 = gX1*gX2, gx22 = gX2*gX2;
    const float gy00 = gY0*gY0, gy01 = gY0*gY1, gy02 = gY0*gY2,
                gy11 = gY1*gY1, gy12 = gY1*gY2, gy22 = gY2*gY2;
    const float sx2 = max_ax[0] * max_ax[0], sy2 = max_ay[0] * max_ay[0];
    const float ex00 = gx00*sx2, ex01 = gx01*sx2, ex02 = gx02*sx2,
                ex11 = gx11*sx2, ex12 = gx12*sx2, ex22 = gx22*sx2;
    const float ey00 = gy00*sy2, ey01 = gy01*sy2, ey02 = gy02*sy2,
                ey11 = gy11*sy2, ey12 = gy12*sy2, ey22 = gy22*sy2;
    const float pv = vstd[0] * vstd[0], pa = astd[0] * astd[0];

    // ---- KF state, BOTH channels per lane (live only in waves 2,3) ----
    float Xx0 = 0.f, Xx1 = 0.f, Xx2 = 0.f;
    float Xy0 = 0.f, Xy1 = 0.f, Xy2 = 0.f;
    float Px00 = 0.f, Px01 = 0.f, Px02 = 0.f, Px11 = 0.f, Px12 = 0.f, Px22 = 0.f;
    float Py00 = 0.f, Py01 = 0.f, Py02 = 0.f, Py11 = 0.f, Py12 = 0.f, Py22 = 0.f;
    if (wv >= 2) {
        Xx0 = hist[be * 40 + 0];
        Xy0 = hist[be * 40 + 1];
        Px00 = rx; Px11 = pv; Px22 = pa;
        Py00 = rx; Py11 = pv; Py22 = pa;   // ref kinit: R_x both channels
    }

    float creg[3][2];
#pragma unroll
    for (int l = 0; l < 3; ++l) { creg[l][0] = 0.f; creg[l][1] = 0.f; }

    // ---- activations: native v_exp path ----
    auto sig = [](float z) { return __builtin_amdgcn_rcpf(1.f + __expf(-z)); };
    auto th  = [](float z) { return fmaf(-2.f, __builtin_amdgcn_rcpf(__expf(2.f * z) + 1.f), 1.f); };

    auto kpred9 = [](float& X0, float& X1, float& X2,
                     float& P00, float& P01, float& P02, float& P11, float& P12, float& P22,
                     float Q00, float Q01, float Q02, float Q11, float Q12, float Q22) {
        X0 = X0 + DT * X1 + HDT * X2;
        X1 = X1 + DT * X2;
        float M00 = P00 + DT * P01 + HDT * P02;
        float M01 = P01 + DT * P11 + HDT * P12;
        float M02 = P02 + DT * P12 + HDT * P22;
        float M11 = P11 + DT * P12;
        float M12 = P12 + DT * P22;
        float M22 = P22;
        P00 = M00 + DT * M01 + HDT * M02 + Q00;
        P01 = M01 + DT * M02 + Q01;
        P02 = M02 + Q02;
        P11 = M11 + DT * M12 + Q11;
        P12 = M12 + Q12;
        P22 = M22 + Q22;
    };
    auto kupd9 = [](float& X0, float& X1, float& X2,
                    float& P00, float& P01, float& P02, float& P11, float& P12, float& P22,
                    float z, float R) {
        float y = z - X0;
        float Sinv = 1.0f / (P00 + R);
        float K0 = P00 * Sinv, K1 = P01 * Sinv, K2 = P02 * Sinv;
        X0 += y * K0; X1 += y * K1; X2 += y * K2;
        float p00 = P00, p01 = P01, p02 = P02;
        P00 = p00 - K0 * p00;
        P01 = p01 - K0 * p01;
        P02 = p02 - K0 * p02;
        P11 = P11 - K1 * p01;
        P12 = P12 - K1 * p02;
        P22 = P22 - K2 * p02;
    };
    auto kf_enc_step = [&](int s) {   // both channels; independent chains interleave
        float zx = hist[be * 40 + s * 2], zy = hist[be * 40 + s * 2 + 1];
        kpred9(Xx0, Xx1, Xx2, Px00, Px01, Px02, Px11, Px12, Px22, ex00, ex01, ex02, ex11, ex12, ex22);
        kupd9 (Xx0, Xx1, Xx2, Px00, Px01, Px02, Px11, Px12, Px22, zx, rx);
        kpred9(Xy0, Xy1, Xy2, Py00, Py01, Py02, Py11, Py12, Py22, ey00, ey01, ey02, ey11, ey12, ey22);
        kupd9 (Xy0, Xy1, Xy2, Py00, Py01, Py02, Py11, Py12, Py22, zy, ry);
    };

    auto packf = [&](const float* v) {
        union { bfrag8 f; unsigned int u[4]; } u;
#pragma unroll
        for (int d = 0; d < 4; ++d) u.u[d] = cvtpk(v[2 * d], v[2 * d + 1]);
        return u.f;
    };
    // XP = [Xx(3), Xy(3), Px flat(9), Py flat(9), pad]; lane supplies elems 8q..8q+7
    auto build_xp = [&]() {
        float v[8];
        if (q == 0)      { v[0]=Xx0;  v[1]=Xx1;  v[2]=Xx2;  v[3]=Xy0;  v[4]=Xy1;  v[5]=Xy2;  v[6]=Px00; v[7]=Px01; }
        else if (q == 1) { v[0]=Px02; v[1]=Px01; v[2]=Px11; v[3]=Px12; v[4]=Px02; v[5]=Px12; v[6]=Px22; v[7]=Py00; }
        else if (q == 2) { v[0]=Py01; v[1]=Py02; v[2]=Py01; v[3]=Py11; v[4]=Py12; v[5]=Py02; v[6]=Py12; v[7]=Py22; }
        else             { v[0]=0.f; v[1]=0.f; v[2]=0.f; v[3]=0.f; v[4]=0.f; v[5]=0.f; v[6]=0.f; v[7]=0.f; }
        return packf(v);
    };
    // wave w: Win MFMA from in-register XP -> x0 feats w*16+q*4+{0..3} -> dst
    auto win_emit = [&](unsigned int* dst) {
        bfrag8 xpf = build_xp();
        f32x4 aw = __builtin_amdgcn_mfma_f32_16x16x32_bf16(winF, xpf, winBv, 0, 0, 0);
        u32x2 pk;
        pk.x = cvtpk(th(aw[0]), th(aw[1]));
        pk.y = cvtpk(th(aw[2]), th(aw[3]));
        *(u32x2*)(dst + ((2 * w + (q >> 1)) * 16 + m) * 4 + (q & 1) * 2) = pk;
    };

    auto gates_from = [&](int l, int j, f32x4 a, float& cv, float& hv) {
        float iv = sig(a[0]), fv = sig(a[1]), gv = th(a[2]), ov = sig(a[3]);
        float c = fmaf(fv, creg[l][j], iv * gv);
        creg[l][j] = c;
        cv = c;
        hv = ov * th(c);
    };

    // ---- LDS zero init ----
    for (int i = tid; i < 3 * 2 * 4 * 16 * 4; i += 256) {
        (&xchC[0][0][0][0][0])[i] = 0;
        (&xchH[0][0][0][0][0])[i] = 0;
    }

    // ---- prologue: waves 2,3 run encoder KF + Win fully in-register (0 barriers) ----
    if (wv >= 2) {
#pragma unroll 1
        for (int s = 0; s < T_HIST - 1; ++s) {
            if (s > 0) kf_enc_step(s);
            win_emit(&xenc[s][0][0][0]);
        }
        kf_enc_step(T_HIST - 1);   // z_19 -> decoder-initial KF state (stays in regs)
    }
    __syncthreads();               // xenc + zero-init visible

    // ---- encoder: diagonal pipeline, phases p = 0..20, ONE barrier each ----
    // phase p: L0 step p, L1 step p-1, L2 step p-2. Writes parity p&1, reads p&1^1.
#pragma unroll 1
    for (int p = 0; p < T_HIST + 1; ++p) {
        const int pw = p & 1, pr = pw ^ 1;
        const bool b0 = (p <= T_HIST - 2);
        const bool b1 = (p >= 1) && (p <= T_HIST - 1);
        const bool b2 = (p >= 2);
        unsigned int cd0, hd0, cd1, hd1, cd2, hd2;
        if (b0) {
            bfrag8 xf = *(const bfrag8*)&xenc[p][q][m][0];
            bfrag8 hf = *(const bfrag8*)&xchH[0][pr][q][m][0];
            f32x4 a = __builtin_amdgcn_mfma_f32_16x16x32_bf16(fragA[0][1][0], hf, biasV[0][0], 0, 0, 0);
            a = __builtin_amdgcn_mfma_f32_16x16x32_bf16(fragA[0][0][0], xf, a, 0, 0, 0);
            f32x4 b = __builtin_amdgcn_mfma_f32_16x16x32_bf16(fragA[0][1][1], hf, biasV[0][1], 0, 0, 0);
            b = __builtin_amdgcn_mfma_f32_16x16x32_bf16(fragA[0][0][1], xf, b, 0, 0, 0);
            float c0, h0, c1, h1;
            gates_from(0, 0, a, c0, h0); gates_from(0, 1, b, c1, h1);
            cd0 = cvtpk(c0, c1); hd0 = cvtpk(h0, h1);
        }
        if (b1) {
            bfrag8 xf = *(const bfrag8*)&xchC[0][pr][q][m][0];
            bfrag8 hf = *(const bfrag8*)&xchH[1][pr][q][m][0];
            f32x4 a = __builtin_amdgcn_mfma_f32_16x16x32_bf16(fragA[1][1][0], hf, biasV[1][0], 0, 0, 0);
            a = __builtin_amdgcn_mfma_f32_16x16x32_bf16(fragA[1][0][0], xf, a, 0, 0, 0);
            f32x4 b = __builtin_amdgcn_mfma_f32_16x16x32_bf16(fragA[1][1][1], hf, biasV[1][1], 0, 0, 0);
            b = __builtin_amdgcn_mfma_f32_16x16x32_bf16(fragA[1][0][1], xf, b, 0, 0, 0);
            float c0, h0, c1, h1;
            gates_from(1, 0, a, c0, h0); gates_from(1, 1, b, c1, h1);
            cd1 = cvtpk(c0, c1); hd1 = cvtpk(h0, h1);
        }
        if (b2) {
            bfrag8 xf = *(const bfrag8*)&xchC[1][pr][q][m][0];
            bfrag8 hf = *(const bfrag8*)&xchH[2][pr][q][m][0];
            f32x4 a = __builtin_amdgcn_mfma_f32_16x16x32_bf16(fragA[2][1][0], hf, biasV[2][0], 0, 0, 0);
            a = __builtin_amdgcn_mfma_f32_16x16x32_bf16(fragA[2][0][0], xf, a, 0, 0, 0);
            f32x4 b = __builtin_amdgcn_mfma_f32_16x16x32_bf16(fragA[2][1][1], hf, biasV[2][1], 0, 0, 0);
            b = __builtin_amdgcn_mfma_f32_16x16x32_bf16(fragA[2][0][1], xf, b, 0, 0, 0);
            float c0, h0, c1, h1;
            gates_from(2, 0, a, c0, h0); gates_from(2, 1, b, c1, h1);
            cd2 = cvtpk(c0, c1); hd2 = cvtpk(h0, h1);
        }
        if (b0) { xchC[0][pw][wv][m][q] = cd0; xchH[0][pw][wv][m][q] = hd0; }
        if (b1) { xchC[1][pw][wv][m][q] = cd1; xchH[1][pw][wv][m][q] = hd1; }
        if (b2) { xchC[2][pw][wv][m][q] = cd2; xchH[2][pw][wv][m][q] = hd2; }
        __syncthreads();
    }

    // ---- transition: final h frags / c2 from pipeline parities ----
    // h0[18] @p18(par0), h1[18] @p19(par1), h2[18]/c2[18] @p20(par0)
    load_phase(1);
    bfrag8 hfragR[3];
    hfragR[0] = *(const bfrag8*)&xchH[0][0][q][m][0];
    hfragR[1] = *(const bfrag8*)&xchH[1][1][q][m][0];
    hfragR[2] = *(const bfrag8*)&xchH[2][0][q][m][0];
    bfrag8 c2f = *(const bfrag8*)&xchC[2][0][q][m][0];
    // (each wave's reads drain at its own next __syncthreads before any write lands)

    auto do_pred = [&](int tout) {
        f32x4 ap = __builtin_amdgcn_mfma_f32_16x16x32_bf16(woutF, c2f, zero4, 0, 0, 0);
        float p0 = ap[0] + wb0, p1 = ap[1] + wb1, p2 = ap[2] + wb2, p3 = ap[3] + wb3;
        Xx2 = DT * p0; Xy2 = DT * p1;
        float qsx = p2 * p2, qsy = p3 * p3;
        kpred9(Xx0, Xx1, Xx2, Px00, Px01, Px02, Px11, Px12, Px22,
               qsx*gx00, qsx*gx01, qsx*gx02, qsx*gx11, qsx*gx12, qsx*gx22);
        kpred9(Xy0, Xy1, Xy2, Py00, Py01, Py02, Py11, Py12, Py22,
               qsy*gy00, qsy*gy01, qsy*gy02, qsy*gy11, qsy*gy12, qsy*gy22);
        if (wv == 2 && q == 0) {
            float* o = out + (size_t)be * (LEN_PRED * 5) + tout * 5;
            o[0] = Xx0; o[1] = Xy0; o[2] = sqrtf(Px00); o[3] = sqrtf(Py00); o[4] = 0.f;
        }
    };

    // ---- decoder: 30 steps, 4 barriers/step, x0 via in-register XP ----
#pragma unroll 1
    for (int t = 0; t < LEN_PRED; ++t) {
        // hoisted hh-MFMAs (all waves; h(t-1) in registers)
        f32x4 ah[3][2];
#pragma unroll
        for (int l = 0; l < 3; ++l)
#pragma unroll
            for (int j = 0; j < 2; ++j)
                ah[l][j] = __builtin_amdgcn_mfma_f32_16x16x32_bf16(fragA[l][1][j], hfragR[l], biasV[l][j], 0, 0, 0);

        if (wv >= 2) {
            if (t > 0) do_pred(t - 1);   // Wout (replicated) -> KF pred -> out store
            win_emit(&x0b[0][0][0]);     // XP in regs -> Win MFMA -> x0 half w
        }
        __syncthreads();   // bar1: x0 visible

        bfrag8 xf = *(const bfrag8*)&x0b[q][m][0];
#pragma unroll
        for (int l = 0; l < 3; ++l) {
            f32x4 a0 = __builtin_amdgcn_mfma_f32_16x16x32_bf16(fragA[l][0][0], xf, ah[l][0], 0, 0, 0);
            f32x4 a1 = __builtin_amdgcn_mfma_f32_16x16x32_bf16(fragA[l][0][1], xf, ah[l][1], 0, 0, 0);
            float c0, h0, c1, h1;
            gates_from(l, 0, a0, c0, h0);
            gates_from(l, 1, a1, c1, h1);
            xchC[l][0][wv][m][q] = cvtpk(c0, c1);
            xchH[l][0][wv][m][q] = cvtpk(h0, h1);
            __syncthreads();   // bar2..4
            xf        = *(const bfrag8*)&xchC[l][0][q][m][0];
            hfragR[l] = *(const bfrag8*)&xchH[l][0][q][m][0];
        }
        c2f = xf;
    }
    if (wv >= 2) do_pred(LEN_PRED - 1);
}

extern "C" void kernel_launch(void* const* d_in, const int* in_sizes, int n_in,
                              void* d_out, int out_size, void* d_ws, size_t ws_size,
                              hipStream_t stream)
{
    const float* hist  = (const float*)d_in[0];
    const float* maxax = (const float*)d_in[1];
    const float* maxay = (const float*)d_in[2];
    const float* vstd  = (const float*)d_in[3];
    const float* astd  = (const float*)d_in[4];
    const float* Rx    = (const float*)d_in[5];
    const float* Ry    = (const float*)d_in[6];
    const float* Gx    = (const float*)d_in[7];
    const float* Gy    = (const float*)d_in[8];
    const float* WinW  = (const float*)d_in[9];
    const float* Winb  = (const float*)d_in[10];
    const float* eWih  = (const float*)d_in[11];
    const float* eWhh  = (const float*)d_in[12];
    const float* ebih  = (const float*)d_in[13];
    const float* ebhh  = (const float*)d_in[14];
    const float* dWih  = (const float*)d_in[15];
    const float* dWhh  = (const float*)d_in[16];
    const float* dbih  = (const float*)d_in[17];
    const float* dbhh  = (const float*)d_in[18];
    const float* WoutW = (const float*)d_in[19];
    const float* Woutb = (const float*)d_in[20];
    char* ws = (char*)d_ws;
    float* out = (float*)d_out;

    prep_kernel<<<202, 256, 0, stream>>>(WinW, eWih, eWhh, ebih, ebhh,
                                         dWih, dWhh, dbih, dbhh, WoutW, ws);
    kalman_lstm_kernel<<<512, 256, 0, stream>>>(hist, maxax, maxay, vstd, astd,
                                                Rx, Ry, Gx, Gy, Winb, Woutb,
                                                ws, out);
}

// Round 15
// 180.659 us; speedup vs baseline: 1.0553x; 1.0553x over previous
//
#include <hip/hip_runtime.h>
#include <math.h>

#define DT   0.1f
#define HDT  0.005f
#define T_HIST 20
#define LEN_PRED 30

typedef __attribute__((ext_vector_type(8))) short bfrag8;   // 8 bf16 = 4 VGPRs
typedef __attribute__((ext_vector_type(4))) float f32x4;
typedef __attribute__((ext_vector_type(2))) unsigned int u32x2;

// d_ws layout (bytes)
#define WS_FRAG   0u        // 96 frags * 512 bf16 * 2B = 98304
#define WS_WIN    98304u    // 2 frags * 1024B (w-major: frag w = Win rows w*16..w*16+15)
#define WS_WOUT   100352u   // 1 frag * 1024B (replicated rows -> pred0..3 in every lane)
#define WS_BIAS   101376u   // 2*3*32*4 floats = 3072B ([ph][l][col][gate])

static __device__ __forceinline__ unsigned short f2bf(float x) {
    union { float f; unsigned int u; } v; v.f = x;
    unsigned int r = v.u + 0x7fffu + ((v.u >> 16) & 1u);   // RNE
    return (unsigned short)(r >> 16);
}

static __device__ __forceinline__ unsigned int cvtpk(float lo, float hi) {
    unsigned int r;
    asm("v_cvt_pk_bf16_f32 %0, %1, %2" : "=v"(r) : "v"(lo), "v"(hi));
    return r;
}

// ---------------- weight prep (UNCHANGED from R7) ----------------
// Layer frag (ph,l,c,t) with t=2*wv+j: A[p][k] = W[gate*32+feat][k],
// gate=p&3, feat = wv*8 + 2*(p>>2) + j.  D row=q*4+r -> lane (q,m) reg r =
// gate r of cell feat wv*8+2q+j; packed c/h dword writes land at
// xch[fg=wv][m][dw=q] (2 lanes/bank, free); reads [q][m] are linear
// lane*16B (conflict-free).
// Win frag (w-major): frag w rows p -> Win row w*16+p.
// Wout frag: REPLICATED rows (p&3) -> every lane's D regs = pred0..3 (no shfl).
// Bias: [ph][l][col=feat][gate].
__global__ void prep_kernel(const float* __restrict__ Win_W,
                            const float* __restrict__ eWih, const float* __restrict__ eWhh,
                            const float* __restrict__ ebih, const float* __restrict__ ebhh,
                            const float* __restrict__ dWih, const float* __restrict__ dWhh,
                            const float* __restrict__ dbih, const float* __restrict__ dbhh,
                            const float* __restrict__ Wout_W,
                            char* __restrict__ ws)
{
    int i = blockIdx.x * blockDim.x + threadIdx.x;
    if (i < 49152) {
        int fi = i >> 9, within = i & 511;
        int lane = within >> 3, jj = within & 7;
        int t = fi & 7, c = (fi >> 3) & 1;
        int pl = fi >> 4;                 // ph*3 + l
        int l = pl % 3, ph = pl / 3;
        int p = lane & 15, q2 = lane >> 4;
        int gate = p & 3;
        int feat = (t >> 1) * 8 + 2 * (p >> 2) + (t & 1);   // (wv,j) mapping
        int row = gate * 32 + feat;
        int k = q2 * 8 + jj;
        const float* W = (c == 0) ? (ph ? dWih : eWih) : (ph ? dWhh : eWhh);
        ((unsigned short*)(ws + WS_FRAG))[i] = f2bf(W[l * 4096 + row * 32 + k]);
    } else if (i < 50176) {
        int i2 = i - 49152;
        int w = i2 >> 9, within = i2 & 511;
        int lane = within >> 3, jj = within & 7;
        int p = lane & 15, q2 = lane >> 4;
        int k = q2 * 8 + jj;
        float v = (k < 24) ? Win_W[(w * 16 + p) * 24 + k] : 0.f;
        ((unsigned short*)(ws + WS_WIN))[i2] = f2bf(v);
    } else if (i < 50688) {
        int i3 = i - 50176;
        int lane = i3 >> 3, jj = i3 & 7;
        int p = lane & 15, q2 = lane >> 4;
        float v = Wout_W[(p & 3) * 32 + q2 * 8 + jj];   // replicated rows
        ((unsigned short*)(ws + WS_WOUT))[i3] = f2bf(v);
    } else if (i < 51456) {
        int b = i - 50688;                 // [ph][l][col][r]
        int ph = b / 384, rem = b % 384;
        int l = rem >> 7, w2 = rem & 127;
        int col = w2 >> 2, r = w2 & 3;
        const float* bi = ph ? dbih : ebih;
        const float* bh = ph ? dbhh : ebhh;
        ((float*)(ws + WS_BIAS))[b] = bi[l * 128 + r * 32 + col] + bh[l * 128 + r * 32 + col];
    }
}

// ---------------- main kernel: 4 waves per 16 batch elems (R7 structure) ----------------
// Wave wv owns cells feat wv*8+2q+{0,1} per lane. KF runs ONLY in waves 2-3,
// one channel per lane (ch=q&1) -> the two channels' serial chains run in
// PARALLEL across lanes (R14 proved in-lane serialization costs +5us).
// Encoder layer-pipelined diagonally (1 barrier/phase, 21 phases). Decoder:
// 4 barriers/step, hoisted hh-MFMAs, replicated-Wout (no shfl), __expf.
// R15 delta: s_setprio(1) around the serial KF segments (prologue + decoder
// regionA). At 2 blocks/CU each SIMD hosts waves of two INDEPENDENT blocks
// at different phases (attn-like regime, m191 +4-7%); priority biases issue
// arbitration toward the chain that sets the block's wall time.
__launch_bounds__(256, 2)
__global__ void kalman_lstm_kernel(const float* __restrict__ hist,
                                   const float* __restrict__ max_ax, const float* __restrict__ max_ay,
                                   const float* __restrict__ vstd, const float* __restrict__ astd,
                                   const float* __restrict__ Rx_, const float* __restrict__ Ry_,
                                   const float* __restrict__ Gx, const float* __restrict__ Gy,
                                   const float* __restrict__ Win_b, const float* __restrict__ Wout_b,
                                   const char* __restrict__ ws, float* __restrict__ out)
{
    __shared__ __align__(16) unsigned int xchC[3][2][4][16][4]; // [layer][parity][fg][m][dw]
    __shared__ __align__(16) unsigned int xchH[3][2][4][16][4];
    __shared__ __align__(16) unsigned int xenc[T_HIST - 1][4][16][4]; // encoder x0 frags
    __shared__ __align__(16) unsigned int x0b[4][16][4];             // decoder x0 frag
    __shared__ __align__(16) unsigned int xps[2][4][16][4];          // XP staging per KF wave

    const int tid  = threadIdx.x;
    const int wv   = tid >> 6;
    const int lane = tid & 63;
    const int q    = lane >> 4;
    const int m    = lane & 15;
    const int be   = blockIdx.x * 16 + m;
    const f32x4 zero4 = {0.f, 0.f, 0.f, 0.f};

    const bfrag8* fragp = (const bfrag8*)(ws + WS_FRAG);
    const f32x4*  biasp = (const f32x4*)(ws + WS_BIAS);

    // ---- per-wave layer weights in registers: [l][c: 0=ih 1=hh][j] ----
    bfrag8 fragA[3][2][2];
    f32x4  biasV[3][2];
    auto load_phase = [&](int ph) {
#pragma unroll
        for (int l = 0; l < 3; ++l) {
#pragma unroll
            for (int c = 0; c < 2; ++c)
#pragma unroll
                for (int j = 0; j < 2; ++j)
                    fragA[l][c][j] = fragp[(((ph * 3 + l) * 2 + c) * 8 + (2 * wv + j)) * 64 + lane];
#pragma unroll
            for (int j = 0; j < 2; ++j)
                biasV[l][j] = biasp[ph * 96 + l * 32 + (wv * 8 + 2 * q + j)];
        }
    };
    load_phase(0);

    // ---- KF-wave operators (waves 2,3; w = wv-2) ----
    const int w  = (wv >= 2) ? (wv - 2) : 0;
    const int ch = q & 1;
    bfrag8 winF = ((const bfrag8*)(ws + WS_WIN))[w * 64 + lane];
    f32x4 winBv;
#pragma unroll
    for (int r = 0; r < 4; ++r) winBv[r] = Win_b[w * 16 + q * 4 + r];
    bfrag8 woutF = ((const bfrag8*)(ws + WS_WOUT))[lane];
    const float wb0 = Wout_b[0], wb1 = Wout_b[1], wb2 = Wout_b[2], wb3 = Wout_b[3];

    // ---- lane-channel Kalman constants + state (waves 2,3 only) ----
    float Rch = 0.f;
    float g00 = 0.f, g01 = 0.f, g02 = 0.f, g11 = 0.f, g12 = 0.f, g22 = 0.f;
    float e00 = 0.f, e01 = 0.f, e02 = 0.f, e11 = 0.f, e12 = 0.f, e22 = 0.f;
    float X0 = 0.f, X1 = 0.f, X2 = 0.f;
    float P00 = 0.f, P01 = 0.f, P02 = 0.f, P11 = 0.f, P12 = 0.f, P22 = 0.f;
    if (wv >= 2) {
        const float rx = Rx_[0] * Rx_[0], ry = Ry_[0] * Ry_[0];
        Rch = ch ? ry : rx;
        float G0, G1, G2, sc;
        if (ch == 0) { G0 = Gx[0]; G1 = Gx[1]; G2 = Gx[2]; sc = max_ax[0]; }
        else         { G0 = Gy[0]; G1 = Gy[1]; G2 = Gy[2]; sc = max_ay[0]; }
        g00 = G0 * G0; g01 = G0 * G1; g02 = G0 * G2;
        g11 = G1 * G1; g12 = G1 * G2; g22 = G2 * G2;
        float s2 = sc * sc;
        e00 = g00 * s2; e01 = g01 * s2; e02 = g02 * s2;
        e11 = g11 * s2; e12 = g12 * s2; e22 = g22 * s2;
        X0 = hist[be * 40 + ch];
        // reference kinit uses R_x for P00 on BOTH channels
        P00 = rx; P11 = vstd[0] * vstd[0]; P22 = astd[0] * astd[0];
    }

    float creg[3][2];
#pragma unroll
    for (int l = 0; l < 3; ++l) { creg[l][0] = 0.f; creg[l][1] = 0.f; }

    // ---- activations: native v_exp path ----
    auto sig = [](float z) { return __builtin_amdgcn_rcpf(1.f + __expf(-z)); };
    auto th  = [](float z) { return fmaf(-2.f, __builtin_amdgcn_rcpf(__expf(2.f * z) + 1.f), 1.f); };

    auto kpredL = [&](float Q00, float Q01, float Q02, float Q11, float Q12, float Q22) {
        X0 = X0 + DT * X1 + HDT * X2;
        X1 = X1 + DT * X2;
        float M00 = P00 + DT * P01 + HDT * P02;
        float M01 = P01 + DT * P11 + HDT * P12;
        float M02 = P02 + DT * P12 + HDT * P22;
        float M11 = P11 + DT * P12;
        float M12 = P12 + DT * P22;
        float M22 = P22;
        P00 = M00 + DT * M01 + HDT * M02 + Q00;
        P01 = M01 + DT * M02 + Q01;
        P02 = M02 + Q02;
        P11 = M11 + DT * M12 + Q11;
        P12 = M12 + Q12;
        P22 = M22 + Q22;
    };
    auto kupdL = [&](float z) {
        float y = z - X0;
        float Sinv = 1.0f / (P00 + Rch);
        float K0 = P00 * Sinv, K1 = P01 * Sinv, K2 = P02 * Sinv;
        X0 += y * K0; X1 += y * K1; X2 += y * K2;
        float p00 = P00, p01 = P01, p02 = P02;
        P00 = p00 - K0 * p00;
        P01 = p01 - K0 * p01;
        P02 = p02 - K0 * p02;
        P11 = P11 - K1 * p01;
        P12 = P12 - K1 * p02;
        P22 = P22 - K2 * p02;
    };
    auto kf_enc_step = [&](int s) {
        float z = hist[be * 40 + s * 2 + ch];
        kpredL(e00, e01, e02, e11, e12, e22);
        kupdL(z);
    };
    // stage XP (feats 0..23) into xps[w]; q0 lanes = x-channel, q1 = y-channel
    auto stage_xp = [&]() {
        if (q < 2) {
            unsigned short* b = (unsigned short*)&xps[w][0][0][0];
            auto wr = [&](int f, float v) { b[(f >> 3) * 128 + m * 8 + (f & 7)] = f2bf(v); };
            int o = ch * 3;
            wr(o + 0, X0); wr(o + 1, X1); wr(o + 2, X2);
            int pb = 6 + ch * 9;
            wr(pb + 0, P00); wr(pb + 1, P01); wr(pb + 2, P02);
            wr(pb + 3, P01); wr(pb + 4, P11); wr(pb + 5, P12);
            wr(pb + 6, P02); wr(pb + 7, P12); wr(pb + 8, P22);
        }
    };

    auto gates_from = [&](int l, int j, f32x4 a, float& cv, float& hv) {
        float iv = sig(a[0]), fv = sig(a[1]), gv = th(a[2]), ov = sig(a[3]);
        float c = fmaf(fv, creg[l][j], iv * gv);
        creg[l][j] = c;
        cv = c;
        hv = ov * th(c);
    };

    // ---- LDS zero init ----
    for (int i = tid; i < 3 * 2 * 4 * 16 * 4; i += 256) {
        (&xchC[0][0][0][0][0])[i] = 0;
        (&xchH[0][0][0][0][0])[i] = 0;
    }

    // ---- prologue: waves 2,3 run encoder KF + Win (wave-internal, 0 barriers) ----
    // setprio(1): this serial chain sets the block's start time; bias issue
    // arbitration vs the co-resident block's waves on the same SIMD.
    if (wv >= 2) {
        __builtin_amdgcn_s_setprio(1);
        for (int i = lane; i < 4 * 16 * 4; i += 64) (&xps[w][0][0][0])[i] = 0;
#pragma unroll 1
        for (int s = 0; s < T_HIST - 1; ++s) {
            if (s > 0) kf_enc_step(s);
            stage_xp();
            bfrag8 bxp = *(const bfrag8*)&xps[w][q][m][0];
            f32x4 aw = __builtin_amdgcn_mfma_f32_16x16x32_bf16(winF, bxp, winBv, 0, 0, 0);
            float v0 = th(aw[0]), v1 = th(aw[1]), v2 = th(aw[2]), v3 = th(aw[3]);
            u32x2 pk; pk.x = cvtpk(v0, v1); pk.y = cvtpk(v2, v3);
            *(u32x2*)&xenc[s][2 * w + (q >> 1)][m][(q & 1) * 2] = pk;
        }
        kf_enc_step(T_HIST - 1);   // z_19 -> decoder-initial KF state (stays in regs)
        __builtin_amdgcn_s_setprio(0);
    }
    __syncthreads();               // xenc + zero-init visible

    // ---- encoder: diagonal pipeline, phases p = 0..20, ONE barrier each ----
    // phase p: L0 step p, L1 step p-1, L2 step p-2. Writes parity p&1, reads p&1^1.
#pragma unroll 1
    for (int p = 0; p < T_HIST + 1; ++p) {
        const int pw = p & 1, pr = pw ^ 1;
        const bool b0 = (p <= T_HIST - 2);
        const bool b1 = (p >= 1) && (p <= T_HIST - 1);
        const bool b2 = (p >= 2);
        unsigned int cd0, hd0, cd1, hd1, cd2, hd2;
        if (b0) {
            bfrag8 xf = *(const bfrag8*)&xenc[p][q][m][0];
            bfrag8 hf = *(const bfrag8*)&xchH[0][pr][q][m][0];
            f32x4 a = __builtin_amdgcn_mfma_f32_16x16x32_bf16(fragA[0][1][0], hf, biasV[0][0], 0, 0, 0);
            a = __builtin_amdgcn_mfma_f32_16x16x32_bf16(fragA[0][0][0], xf, a, 0, 0, 0);
            f32x4 b = __builtin_amdgcn_mfma_f32_16x16x32_bf16(fragA[0][1][1], hf, biasV[0][1], 0, 0, 0);
            b = __builtin_amdgcn_mfma_f32_16x16x32_bf16(fragA[0][0][1], xf, b, 0, 0, 0);
            float c0, h0, c1, h1;
            gates_from(0, 0, a, c0, h0); gates_from(0, 1, b, c1, h1);
            cd0 = cvtpk(c0, c1); hd0 = cvtpk(h0, h1);
        }
        if (b1) {
            bfrag8 xf = *(const bfrag8*)&xchC[0][pr][q][m][0];
            bfrag8 hf = *(const bfrag8*)&xchH[1][pr][q][m][0];
            f32x4 a = __builtin_amdgcn_mfma_f32_16x16x32_bf16(fragA[1][1][0], hf, biasV[1][0], 0, 0, 0);
            a = __builtin_amdgcn_mfma_f32_16x16x32_bf16(fragA[1][0][0], xf, a, 0, 0, 0);
            f32x4 b = __builtin_amdgcn_mfma_f32_16x16x32_bf16(fragA[1][1][1], hf, biasV[1][1], 0, 0, 0);
            b = __builtin_amdgcn_mfma_f32_16x16x32_bf16(fragA[1][0][1], xf, b, 0, 0, 0);
            float c0, h0, c1, h1;
            gates_from(1, 0, a, c0, h0); gates_from(1, 1, b, c1, h1);
            cd1 = cvtpk(c0, c1); hd1 = cvtpk(h0, h1);
        }
        if (b2) {
            bfrag8 xf = *(const bfrag8*)&xchC[1][pr][q][m][0];
            bfrag8 hf = *(const bfrag8*)&xchH[2][pr][q][m][0];
            f32x4 a = __builtin_amdgcn_mfma_f32_16x16x32_bf16(fragA[2][1][0], hf, biasV[2][0], 0, 0, 0);
            a = __builtin_amdgcn_mfma_f32_16x16x32_bf16(fragA[2][0][0], xf, a, 0, 0, 0);
            f32x4 b = __builtin_amdgcn_mfma_f32_16x16x32_bf16(fragA[2][1][1], hf, biasV[2][1], 0, 0, 0);
            b = __builtin_amdgcn_mfma_f32_16x16x32_bf16(fragA[2][0][1], xf, b, 0, 0, 0);
            float c0, h0, c1, h1;
            gates_from(2, 0, a, c0, h0); gates_from(2, 1, b, c1, h1);
            cd2 = cvtpk(c0, c1); hd2 = cvtpk(h0, h1);
        }
        if (b0) { xchC[0][pw][wv][m][q] = cd0; xchH[0][pw][wv][m][q] = hd0; }
        if (b1) { xchC[1][pw][wv][m][q] = cd1; xchH[1][pw][wv][m][q] = hd1; }
        if (b2) { xchC[2][pw][wv][m][q] = cd2; xchH[2][pw][wv][m][q] = hd2; }
        __syncthreads();
    }

    // ---- transition: final h frags / c2 from pipeline parities ----
    // h0[18] @p18(par0), h1[18] @p19(par1), h2[18]/c2[18] @p20(par0)
    load_phase(1);
    bfrag8 hfragR[3];
    hfragR[0] = *(const bfrag8*)&xchH[0][0][q][m][0];
    hfragR[1] = *(const bfrag8*)&xchH[1][1][q][m][0];
    hfragR[2] = *(const bfrag8*)&xchH[2][0][q][m][0];
    bfrag8 c2f = *(const bfrag8*)&xchC[2][0][q][m][0];
    // (each wave's reads drain at its own next __syncthreads before any write lands)

    auto do_pred = [&](int tout) {
        f32x4 ap = __builtin_amdgcn_mfma_f32_16x16x32_bf16(woutF, c2f, zero4, 0, 0, 0);
        float pe = ch ? (ap[1] + wb1) : (ap[0] + wb0);
        float qe = ch ? (ap[3] + wb3) : (ap[2] + wb2);
        X2 = DT * pe;
        float qs = qe * qe;
        kpredL(qs * g00, qs * g01, qs * g02, qs * g11, qs * g12, qs * g22);
        if (wv == 2 && q < 2) {
            float* o = out + (size_t)be * (LEN_PRED * 5) + tout * 5;
            if (ch == 0) { o[0] = X0; o[2] = sqrtf(P00); }
            else         { o[1] = X0; o[3] = sqrtf(P00); o[4] = 0.f; }
        }
    };

    // ---- decoder: 30 steps, 4 barriers/step ----
#pragma unroll 1
    for (int t = 0; t < LEN_PRED; ++t) {
        // hoisted hh-MFMAs (all waves; h(t-1) in registers)
        f32x4 ah[3][2];
#pragma unroll
        for (int l = 0; l < 3; ++l)
#pragma unroll
            for (int j = 0; j < 2; ++j)
                ah[l][j] = __builtin_amdgcn_mfma_f32_16x16x32_bf16(fragA[l][1][j], hfragR[l], biasV[l][j], 0, 0, 0);

        if (wv >= 2) {
            // serial segment on the block's critical path: raise priority
            __builtin_amdgcn_s_setprio(1);
            if (t > 0) do_pred(t - 1);   // Wout (replicated) -> KF pred -> out store
            stage_xp();
            bfrag8 bxp = *(const bfrag8*)&xps[w][q][m][0];
            f32x4 aw = __builtin_amdgcn_mfma_f32_16x16x32_bf16(winF, bxp, winBv, 0, 0, 0);
            float v0 = th(aw[0]), v1 = th(aw[1]), v2 = th(aw[2]), v3 = th(aw[3]);
            u32x2 pk; pk.x = cvtpk(v0, v1); pk.y = cvtpk(v2, v3);
            *(u32x2*)&x0b[2 * w + (q >> 1)][m][(q & 1) * 2] = pk;
            __builtin_amdgcn_s_setprio(0);
        }
        __syncthreads();   // bar1: x0 visible

        bfrag8 xf = *(const bfrag8*)&x0b[q][m][0];
#pragma unroll
        for (int l = 0; l < 3; ++l) {
            f32x4 a0 = __builtin_amdgcn_mfma_f32_16x16x32_bf16(fragA[l][0][0], xf, ah[l][0], 0, 0, 0);
            f32x4 a1 = __builtin_amdgcn_mfma_f32_16x16x32_bf16(fragA[l][0][1], xf, ah[l][1], 0, 0, 0);
            float c0, h0, c1, h1;
            gates_from(l, 0, a0, c0, h0);
            gates_from(l, 1, a1, c1, h1);
            xchC[l][0][wv][m][q] = cvtpk(c0, c1);
            xchH[l][0][wv][m][q] = cvtpk(h0, h1);
            __syncthreads();   // bar2..4
            xf        = *(const bfrag8*)&xchC[l][0][q][m][0];
            hfragR[l] = *(const bfrag8*)&xchH[l][0][q][m][0];
        }
        c2f = xf;
    }
    do_pred(LEN_PRED - 1);
}

extern "C" void kernel_launch(void* const* d_in, const int* in_sizes, int n_in,
                              void* d_out, int out_size, void* d_ws, size_t ws_size,
                              hipStream_t stream)
{
    const float* hist  = (const float*)d_in[0];
    const float* maxax = (const float*)d_in[1];
    const float* maxay = (const float*)d_in[2];
    const float* vstd  = (const float*)d_in[3];
    const float* astd  = (const float*)d_in[4];
    const float* Rx    = (const float*)d_in[5];
    const float* Ry    = (const float*)d_in[6];
    const float* Gx    = (const float*)d_in[7];
    const float* Gy    = (const float*)d_in[8];
    const float* WinW  = (const float*)d_in[9];
    const float* Winb  = (const float*)d_in[10];
    const float* eWih  = (const float*)d_in[11];
    const float* eWhh  = (const float*)d_in[12];
    const float* ebih  = (const float*)d_in[13];
    const float* ebhh  = (const float*)d_in[14];
    const float* dWih  = (const float*)d_in[15];
    const float* dWhh  = (const float*)d_in[16];
    const float* dbih  = (const float*)d_in[17];
    const float* dbhh  = (const float*)d_in[18];
    const float* WoutW = (const float*)d_in[19];
    const float* Woutb = (const float*)d_in[20];
    char* ws = (char*)d_ws;
    float* out = (float*)d_out;

    prep_kernel<<<202, 256, 0, stream>>>(WinW, eWih, eWhh, ebih, ebhh,
                                         dWih, dWhh, dbih, dbhh, WoutW, ws);
    kalman_lstm_kernel<<<512, 256, 0, stream>>>(hist, maxax, maxay, vstd, astd,
                                                Rx, Ry, Gx, Gy, Winb, Woutb,
                                                ws, out);
}